// Round 7
// baseline (206.054 us; speedup 1.0000x reference)
//
#include <hip/hip_runtime.h>
#include <stdint.h>

typedef unsigned short u16;
typedef __attribute__((ext_vector_type(8))) short short8;
typedef __attribute__((ext_vector_type(4))) float floatx4;

#define NB 32
#define NC 256
#define NH 32
#define NW 32
#define NO 256
#define NPIX (NH*NW)     // 1024
#define KPIX 9
#define NG 9             // subarrays (groups)
#define RUN 32           // padded run length (per kernel-tap within group)
#define GK (NG*RUN)      // 288 k-slots per group
#define KTOT (NG*GK)     // 2592 k-slots
#define PADH 34
#define PADSP (PADH*PADH)       // 1156
#define QA_BSTRIDE (PADSP*NC)   // 295936 elems per batch

#define AS1 __attribute__((address_space(1)))
#define AS3 __attribute__((address_space(3)))

// ---------------- fused: per-block absmax slots + zero qa halo borders ----------------
__global__ void fused_pre(const float4* __restrict__ x4, int nx4,
                          const float4* __restrict__ w4, int nw4,
                          float* __restrict__ pmax, u16* __restrict__ qa) {
  int bid = blockIdx.x;
  if (bid >= 1088) {
    int zb = bid - 1088;              // 9 blocks per batch
    int b = zb / 9;
    int rem = (zb % 9) * 256 + threadIdx.x;   // need <2112 (132 px * 16 ch-groups)
    if (rem >= 2112) return;
    int pb = rem >> 4, c16 = rem & 15;
    int y, x;
    if (pb < 68) { y = (pb >= 34) ? 33 : 0; x = pb % 34; }
    else { int q = pb - 68; y = 1 + (q >> 1); x = (q & 1) ? 33 : 0; }
    uint4 z; z.x = z.y = z.z = z.w = 0u;
    *(uint4*)(qa + ((size_t)(b * PADH + y) * PADH + x) * NC + c16 * 16) = z;
    return;
  }
  const float4* p; int n4; int nb, b0;
  if (bid < 1024) { p = x4; n4 = nx4; nb = 1024; b0 = bid; }
  else            { p = w4; n4 = nw4; nb = 64;   b0 = bid - 1024; }
  float m = 0.f;
  for (int i = b0 * blockDim.x + threadIdx.x; i < n4; i += nb * blockDim.x) {
    float4 v = p[i];
    m = fmaxf(m, fmaxf(fmaxf(fabsf(v.x), fabsf(v.y)), fmaxf(fabsf(v.z), fabsf(v.w))));
  }
#pragma unroll
  for (int off = 32; off > 0; off >>= 1)
    m = fmaxf(m, __shfl_down(m, off, 64));
  __shared__ float sm[4];
  int lane = threadIdx.x & 63, wv = threadIdx.x >> 6;
  if (lane == 0) sm[wv] = m;
  __syncthreads();
  if (threadIdx.x == 0)
    pmax[bid] = fmaxf(fmaxf(sm[0], sm[1]), fmaxf(sm[2], sm[3]));
}

// helper: reduce the 1024 x-slots and 64 w-slots
__device__ inline void reduce_pmax(const float* pmax, int tid, int nthreads,
                                   float* sred, float& mx_out, float& mw_out) {
  const float4* pf4 = (const float4*)pmax;
  float mx = 0.f, mw = 0.f;
  for (int t = tid; t < 256; t += nthreads) {
    float4 v = pf4[t];
    mx = fmaxf(mx, fmaxf(fmaxf(v.x, v.y), fmaxf(v.z, v.w)));
  }
  if (tid < 16) {
    float4 v = pf4[256 + tid];
    mw = fmaxf(fmaxf(v.x, v.y), fmaxf(v.z, v.w));
  }
#pragma unroll
  for (int off = 32; off > 0; off >>= 1) {
    mx = fmaxf(mx, __shfl_down(mx, off, 64));
    mw = fmaxf(mw, __shfl_down(mw, off, 64));
  }
  int lane = tid & 63, wv = tid >> 6, nw = nthreads >> 6;
  if (lane == 0) { sred[wv] = mx; sred[8 + wv] = mw; }
  __syncthreads();
  mx = sred[0]; mw = sred[8];
  for (int i = 1; i < nw; i++) { mx = fmaxf(mx, sred[i]); mw = fmaxf(mw, sred[8 + i]); }
  mx_out = mx; mw_out = mw;
}

// ---------------- fused quantization: acts + weights ----------------
// Weight packing (from R4): slot j of (g,r) maps to channel cw(g)+j with
// cw = (256g/9)&~3 UNIFORM across the group's 9 taps (verified subset property).
__global__ void fused_quant(const float* __restrict__ x, const float* __restrict__ w,
                            const float* __restrict__ pmax,
                            u16* __restrict__ qa, u16* __restrict__ wq,
                            float* __restrict__ lossp) {
  __shared__ float sred[16];
  float mx, mw;
  reduce_pmax(pmax, threadIdx.x, 256, sred, mx, mw);
  int bid = blockIdx.x, tid = threadIdx.x;
  if (bid < 1024) {
    __shared__ u16 ts[32][264];        // [x][c], row stride 264 (16B-aligned rows)
    double s = (double)mx + 1e-12;
    double inv = 255.0 / s;
    int b = bid >> 5, y = bid & 31;
    const float4* x4 = (const float4*)x;
    int xc = tid & 7, crow = tid >> 3;
#pragma unroll
    for (int it = 0; it < 8; it++) {
      int c = crow + 32 * it;
      float4 v = x4[((size_t)(b * NC + c) * NH + y) * 8 + xc];
      float q0 = (float)rint((double)v.x * inv);
      float q1 = (float)rint((double)v.y * inv);
      float q2 = (float)rint((double)v.z * inv);
      float q3 = (float)rint((double)v.w * inv);
      ts[xc * 4 + 0][c] = (u16)(__float_as_uint(q0) >> 16);
      ts[xc * 4 + 1][c] = (u16)(__float_as_uint(q1) >> 16);
      ts[xc * 4 + 2][c] = (u16)(__float_as_uint(q2) >> 16);
      ts[xc * 4 + 3][c] = (u16)(__float_as_uint(q3) >> 16);
    }
    __syncthreads();
    int xx = tid >> 3, qwl = tid & 7;
    u16* orow = qa + ((size_t)(b * PADH + y + 1) * PADH + (xx + 1)) * NC;
#pragma unroll
    for (int it = 0; it < 4; it++) {
      int qw = qwl + 8 * it;
      *(uint4*)(orow + qw * 8) = *(const uint4*)&ts[xx][qw * 8];
    }
    return;
  }
  // ---- weights: 2592 blocks cover NO*KTOT = 663552 slots exactly ----
  double s = (double)mw + 1e-12;
  double inv = 15.0 / s;
  int idx = (bid - 1024) * 256 + tid;
  if (idx == 0) *lossp = 0.0f;                  // a_loss output
  int o = idx / KTOT, kk = idx % KTOT;
  int g = kk / GK, rem = kk % GK;
  int r = rem / RUN, j = rem % RUN;
  int clo = (256 * g - r + 8) / 9;
  int chi = (256 * (g + 1) - r + 8) / 9; if (chi > NC) chi = NC;
  int cst = ((256 * g) / 9) & ~3;               // UNIFORM per-group window start
  int c = cst + j;
  float val = 0.f;
  if (c >= clo && c < chi) {
    float wv = w[((size_t)o * NC + c) * KPIX + r];
    val = (float)rint((double)wv * inv);
  }
  wq[idx] = (u16)(__float_as_uint(val) >> 16);
}

// ---------------- fused GEMM + per-group ADC ----------------
// R6 structure (drain frame, conflict-free rotated slab, precomputed addresses,
// f64 ADC fold) at MAX OCCUPANCY: tile 128x64, grid (256,4) = 1024 blocks =
// 4 blocks/CU x 8 waves = 32 waves/CU = 8 waves/SIMD (R6 was 2 blocks/CU = 4/SIMD;
// its -17% win confirmed latency-bound-by-wave-count, and no pipe is near ceiling).
// 8 waves of 32x32 output: wm=(wv&3)*32, wn=(wv>>2)*32, acc[2][2]. VGPR kept <=64
// (the m69 occupancy cliff) via addrA9[9] + mi*512 (P->P+16 preserves (P>>1)&3) and
// __launch_bounds__(512,8). B staging: 768 slots/512 thr (i0: all, runs 0-1;
// i1: tid<256, run 2) -- row=(tid>>2)&63 and jsrc identical for both (512 = 0 mod 8
// slots), same proven swizzle algebra, B-read row stride unchanged (32 u16) -> 0
// conflicts. B staged total unchanged (340 MB); slab dup 2x = +6.8 MB (negligible).
// Per-wave LDS reads/chunk drop 18->12 b128. Numerics byte-identical.
__global__ __launch_bounds__(512, 8) void gemm_adc(const u16* __restrict__ qa,
                                                   const u16* __restrict__ wq,
                                                   const float* __restrict__ pmax,
                                                   float* __restrict__ out) {
  __shared__ __align__(16) u16 lB[6144];      // 12288 B: 3 runs x 64 rows x 32
  __shared__ __align__(16) u16 sA[6528];      // 13056 B: 204 px x 32 ch (rotated)
  __shared__ float sred[16];
  const int tid = threadIdx.x;
  float mx, mw;
  reduce_pmax(pmax, tid, 512, sred, mx, mw);

  const int mblk = blockIdx.x, nblk = blockIdx.y;
  const int b = mblk >> 3;
  const int p0 = (mblk & 7) * 128;        // pixel base (4 image rows of 32)
  const int y0 = (mblk & 7) * 4;          // slab top row in padded coords
  const int n0 = nblk * 64;
  const int lane = tid & 63, wv = tid >> 6;
  const int wm = (wv & 3) * 32, wn = (wv >> 2) * 32;
  const int fm = lane & 15, fq = lane >> 4;
  const int swz = (fq + ((fm >> 1) & 3)) & 3;

  double sa = (double)mx + 1e-12;
  double sw = (double)mw + 1e-12;
  double Sstep = sa * sw * 0.999 / 459.0;   // I/step = intsum * Sstep

  // ---- precompute 9 A-fragment LDS addresses (mi=0); mi offset is +512 ----
  const int OFS[9] = {0, 1, 2, 34, 35, 36, 68, 69, 70};   // rc*34 + ri
  int addrA9[9];
  {
    int pr = wm + fm;
    int pixb = (pr >> 5) * 34 + (pr & 31);
#pragma unroll
    for (int t = 0; t < 9; t++) {
      int P = pixb + OFS[t];
      addrA9[t] = P * 32 + (((fq + ((P >> 1) & 3)) & 3) << 3);
    }
  }
  // B read offsets (lane-constant); row stride 32 u16 (same proven pattern)
  int bno[2];
#pragma unroll
  for (int ni = 0; ni < 2; ni++) bno[ni] = (wn + ni * 16 + fm) * RUN + swz * 8;

  // B staging geometry: 768 slots; i0: s=tid (runs 0-1), i1: s=512+tid, tid<256
  // (run 2). row=(tid>>2)&63, jsrc identical for both loads (512 == 0 mod 8 slots).
  const int jsrc = ((tid & 3) - ((tid >> 3) & 3)) & 3;
  const u16* Bb = wq + (size_t)(n0 + ((tid >> 2) & 63)) * KTOT + jsrc * 8;
  const int brun0 = (tid >> 8) * RUN;     // k-offset of i0's run (0 or 32)

  // slab staging geometry: 816 slots; i0: s=tid (all), i1: s=512+tid (tid<304)
  const u16* Abase = qa + (size_t)b * QA_BSTRIDE + (size_t)y0 * PADH * NC;
  int soff[2], sdst[2];
#pragma unroll
  for (int i = 0; i < 2; i++) {
    int s = i * 512 + tid;
    soff[i] = (s >> 2) * NC + ((((s & 3) - ((s >> 3) & 3)) & 3) << 3);
    sdst[i] = s * 8;
  }

  floatx4 acc[2][2];
  float tot[2][2][4];
#pragma unroll
  for (int mi = 0; mi < 2; mi++)
#pragma unroll
    for (int ni = 0; ni < 2; ni++)
#pragma unroll
      for (int rr = 0; rr < 4; rr++) { acc[mi][ni][rr] = 0.f; tot[mi][ni][rr] = 0.f; }

  auto STAGE_SLAB = [&](int gp) {
    int cw = ((256 * gp) / 9) & ~3;
    const u16* srcg = Abase + cw;
    __builtin_amdgcn_global_load_lds((const AS1 void*)(srcg + soff[0]),
                                     (AS3 void*)&sA[sdst[0]], 16, 0, 0);
    if (tid < 304)
      __builtin_amdgcn_global_load_lds((const AS1 void*)(srcg + soff[1]),
                                       (AS3 void*)&sA[sdst[1]], 16, 0, 0);
  };
  auto STAGE_B = [&](int kb0) {
    __builtin_amdgcn_global_load_lds((const AS1 void*)(Bb + kb0 + brun0),
                                     (AS3 void*)&lB[tid * 8], 16, 0, 0);
    if (tid < 256)
      __builtin_amdgcn_global_load_lds((const AS1 void*)(Bb + kb0 + 2 * RUN),
                                       (AS3 void*)&lB[(512 + tid) * 8], 16, 0, 0);
  };
  auto FOLD = [&]() {
#pragma unroll
    for (int mi = 0; mi < 2; mi++)
#pragma unroll
      for (int ni = 0; ni < 2; ni++)
#pragma unroll
        for (int rr = 0; rr < 4; rr++) {
          double d = (double)acc[mi][ni][rr] * Sstep;
          float tf = (float)rint(d);
          tf = fminf(fmaxf(tf, -128.f), 127.f);
          tot[mi][ni][rr] += tf;
          acc[mi][ni][rr] = 0.f;
        }
  };

#pragma unroll 1
  for (int g = 0; g < NG; g++) {
    // stage slab(g) + B(g,rc=0); previous group's reads closed by its last barrier
    STAGE_SLAB(g);
    STAGE_B(g * GK);
    if (g > 0) FOLD();           // register-only, overlaps the in-flight loads
#pragma unroll
    for (int rc = 0; rc < 3; rc++) {
      __syncthreads();           // staged chunk landed (implicit vmcnt drain)
      // ---- 3 runs x 4 MFMA per wave ----
#pragma unroll
      for (int ri = 0; ri < 3; ri++) {
        short8 afr[2], bfr[2];
#pragma unroll
        for (int mi = 0; mi < 2; mi++)
          afr[mi] = *(const short8*)&sA[addrA9[rc * 3 + ri] + mi * 512];
#pragma unroll
        for (int ni = 0; ni < 2; ni++)
          bfr[ni] = *(const short8*)&lB[ri * 2048 + bno[ni]];
#pragma unroll
        for (int mi = 0; mi < 2; mi++)
#pragma unroll
          for (int ni = 0; ni < 2; ni++)
            acc[mi][ni] = __builtin_amdgcn_mfma_f32_16x16x32_bf16(afr[mi], bfr[ni], acc[mi][ni], 0, 0, 0);
      }
      __syncthreads();           // reads done before overwrite
      if (rc < 2) STAGE_B(g * GK + (rc + 1) * 96);
    }
  }
  // ---- final group's ADC fold ----
#pragma unroll
  for (int mi = 0; mi < 2; mi++)
#pragma unroll
    for (int ni = 0; ni < 2; ni++)
#pragma unroll
      for (int rr = 0; rr < 4; rr++) {
        double d = (double)acc[mi][ni][rr] * Sstep;
        float tf = (float)rint(d);
        tf = fminf(fmaxf(tf, -128.f), 127.f);
        tot[mi][ni][rr] += tf;
      }

  // ---- epilogue ----
#pragma unroll
  for (int mi = 0; mi < 2; mi++)
#pragma unroll
    for (int ni = 0; ni < 2; ni++) {
      int o = n0 + wn + ni * 16 + fm;
      int p = p0 + wm + mi * 16 + fq * 4;
      float4 o4;
      o4.x = tot[mi][ni][0] * 1e-3f;
      o4.y = tot[mi][ni][1] * 1e-3f;
      o4.z = tot[mi][ni][2] * 1e-3f;
      o4.w = tot[mi][ni][3] * 1e-3f;
      *(float4*)(out + ((size_t)(b * NO + o)) * NPIX + p) = o4;
    }
}

extern "C" void kernel_launch(void* const* d_in, const int* in_sizes, int n_in,
                              void* d_out, int out_size, void* d_ws, size_t ws_size,
                              hipStream_t stream) {
  const float* x = (const float*)d_in[0];
  const float* w = (const float*)d_in[1];
  float* out = (float*)d_out;

  float* pmax = (float*)d_ws;                                // 1088 slots
  u16* qa = (u16*)((char*)d_ws + 8192);                      // padded acts: 18,939,904 B
  u16* wq = (u16*)((char*)d_ws + 8192 + 18939904 + 8192);    // weights: 256*2592*2 B

  fused_pre<<<1376, 256, 0, stream>>>((const float4*)x, (NB * NC * NH * NW) / 4,
                                      (const float4*)w, (NO * NC * KPIX) / 4,
                                      pmax, qa);
  fused_quant<<<1024 + 2592, 256, 0, stream>>>(x, w, pmax, qa, wq, out + (out_size - 1));
  gemm_adc<<<dim3(256, 4), 512, 0, stream>>>(qa, wq, pmax, out);
}

// Round 8
// 153.303 us; speedup vs baseline: 1.3441x; 1.3441x over previous
//
#include <hip/hip_runtime.h>
#include <stdint.h>

typedef unsigned short u16;
typedef __attribute__((ext_vector_type(8))) short short8;
typedef __attribute__((ext_vector_type(4))) float floatx4;

#define NB 32
#define NC 256
#define NH 32
#define NW 32
#define NO 256
#define NPIX (NH*NW)     // 1024
#define KPIX 9
#define NG 9             // subarrays (groups)
#define RUN 32           // padded run length (per kernel-tap within group)
#define GK (NG*RUN)      // 288 k-slots per group
#define KTOT (NG*GK)     // 2592 k-slots
#define PADH 34
#define PADSP (PADH*PADH)       // 1156
#define QA_BSTRIDE (PADSP*NC)   // 295936 elems per batch

#define AS1 __attribute__((address_space(1)))
#define AS3 __attribute__((address_space(3)))

// ---------------- fused: per-block absmax slots + zero qa halo borders ----------------
__global__ void fused_pre(const float4* __restrict__ x4, int nx4,
                          const float4* __restrict__ w4, int nw4,
                          float* __restrict__ pmax, u16* __restrict__ qa) {
  int bid = blockIdx.x;
  if (bid >= 1088) {
    int zb = bid - 1088;              // 9 blocks per batch
    int b = zb / 9;
    int rem = (zb % 9) * 256 + threadIdx.x;   // need <2112 (132 px * 16 ch-groups)
    if (rem >= 2112) return;
    int pb = rem >> 4, c16 = rem & 15;
    int y, x;
    if (pb < 68) { y = (pb >= 34) ? 33 : 0; x = pb % 34; }
    else { int q = pb - 68; y = 1 + (q >> 1); x = (q & 1) ? 33 : 0; }
    uint4 z; z.x = z.y = z.z = z.w = 0u;
    *(uint4*)(qa + ((size_t)(b * PADH + y) * PADH + x) * NC + c16 * 16) = z;
    return;
  }
  const float4* p; int n4; int nb, b0;
  if (bid < 1024) { p = x4; n4 = nx4; nb = 1024; b0 = bid; }
  else            { p = w4; n4 = nw4; nb = 64;   b0 = bid - 1024; }
  float m = 0.f;
  for (int i = b0 * blockDim.x + threadIdx.x; i < n4; i += nb * blockDim.x) {
    float4 v = p[i];
    m = fmaxf(m, fmaxf(fmaxf(fabsf(v.x), fabsf(v.y)), fmaxf(fabsf(v.z), fabsf(v.w))));
  }
#pragma unroll
  for (int off = 32; off > 0; off >>= 1)
    m = fmaxf(m, __shfl_down(m, off, 64));
  __shared__ float sm[4];
  int lane = threadIdx.x & 63, wv = threadIdx.x >> 6;
  if (lane == 0) sm[wv] = m;
  __syncthreads();
  if (threadIdx.x == 0)
    pmax[bid] = fmaxf(fmaxf(sm[0], sm[1]), fmaxf(sm[2], sm[3]));
}

// helper: reduce the 1024 x-slots and 64 w-slots
__device__ inline void reduce_pmax(const float* pmax, int tid, int nthreads,
                                   float* sred, float& mx_out, float& mw_out) {
  const float4* pf4 = (const float4*)pmax;
  float mx = 0.f, mw = 0.f;
  for (int t = tid; t < 256; t += nthreads) {
    float4 v = pf4[t];
    mx = fmaxf(mx, fmaxf(fmaxf(v.x, v.y), fmaxf(v.z, v.w)));
  }
  if (tid < 16) {
    float4 v = pf4[256 + tid];
    mw = fmaxf(fmaxf(v.x, v.y), fmaxf(v.z, v.w));
  }
#pragma unroll
  for (int off = 32; off > 0; off >>= 1) {
    mx = fmaxf(mx, __shfl_down(mx, off, 64));
    mw = fmaxf(mw, __shfl_down(mw, off, 64));
  }
  int lane = tid & 63, wv = tid >> 6, nw = nthreads >> 6;
  if (lane == 0) { sred[wv] = mx; sred[8 + wv] = mw; }
  __syncthreads();
  mx = sred[0]; mw = sred[8];
  for (int i = 1; i < nw; i++) { mx = fmaxf(mx, sred[i]); mw = fmaxf(mw, sred[8 + i]); }
  mx_out = mx; mw_out = mw;
}

// ---------------- fused quantization: acts + weights ----------------
// Weight packing (from R4): slot j of (g,r) maps to channel cw(g)+j with
// cw = (256g/9)&~3 UNIFORM across the group's 9 taps (verified subset property).
__global__ void fused_quant(const float* __restrict__ x, const float* __restrict__ w,
                            const float* __restrict__ pmax,
                            u16* __restrict__ qa, u16* __restrict__ wq,
                            float* __restrict__ lossp) {
  __shared__ float sred[16];
  float mx, mw;
  reduce_pmax(pmax, threadIdx.x, 256, sred, mx, mw);
  int bid = blockIdx.x, tid = threadIdx.x;
  if (bid < 1024) {
    __shared__ u16 ts[32][264];        // [x][c], row stride 264 (16B-aligned rows)
    double s = (double)mx + 1e-12;
    double inv = 255.0 / s;
    int b = bid >> 5, y = bid & 31;
    const float4* x4 = (const float4*)x;
    int xc = tid & 7, crow = tid >> 3;
#pragma unroll
    for (int it = 0; it < 8; it++) {
      int c = crow + 32 * it;
      float4 v = x4[((size_t)(b * NC + c) * NH + y) * 8 + xc];
      float q0 = (float)rint((double)v.x * inv);
      float q1 = (float)rint((double)v.y * inv);
      float q2 = (float)rint((double)v.z * inv);
      float q3 = (float)rint((double)v.w * inv);
      ts[xc * 4 + 0][c] = (u16)(__float_as_uint(q0) >> 16);
      ts[xc * 4 + 1][c] = (u16)(__float_as_uint(q1) >> 16);
      ts[xc * 4 + 2][c] = (u16)(__float_as_uint(q2) >> 16);
      ts[xc * 4 + 3][c] = (u16)(__float_as_uint(q3) >> 16);
    }
    __syncthreads();
    int xx = tid >> 3, qwl = tid & 7;
    u16* orow = qa + ((size_t)(b * PADH + y + 1) * PADH + (xx + 1)) * NC;
#pragma unroll
    for (int it = 0; it < 4; it++) {
      int qw = qwl + 8 * it;
      *(uint4*)(orow + qw * 8) = *(const uint4*)&ts[xx][qw * 8];
    }
    return;
  }
  // ---- weights: 2592 blocks cover NO*KTOT = 663552 slots exactly ----
  double s = (double)mw + 1e-12;
  double inv = 15.0 / s;
  int idx = (bid - 1024) * 256 + tid;
  if (idx == 0) *lossp = 0.0f;                  // a_loss output
  int o = idx / KTOT, kk = idx % KTOT;
  int g = kk / GK, rem = kk % GK;
  int r = rem / RUN, j = rem % RUN;
  int clo = (256 * g - r + 8) / 9;
  int chi = (256 * (g + 1) - r + 8) / 9; if (chi > NC) chi = NC;
  int cst = ((256 * g) / 9) & ~3;               // UNIFORM per-group window start
  int c = cst + j;
  float val = 0.f;
  if (c >= clo && c < chi) {
    float wv = w[((size_t)o * NC + c) * KPIX + r];
    val = (float)rint((double)wv * inv);
  }
  wq[idx] = (u16)(__float_as_uint(val) >> 16);
}

// ---------------- fused GEMM + per-group ADC ----------------
// R7 structure (tile 128x64, grid (256,4) = 1024 blocks, 8 waves of 32x32, drain
// frame, conflict-free rotated slab, addrA9 + mi*512, f64 ADC fold) with the
// LAUNCH_BOUNDS FIX: the 2nd arg is CUDA-style MIN BLOCKS PER CU. Round history
// proves it: (256,2)->cap256->112 VGPR; (512,2)->cap128->128; (512,4)->cap64->64;
// (512,8)->cap32->SPILL (R7: VGPR=32, FETCH 186MB, WRITE 272MB, 2x slower).
// Correct setting for 4 blocks/CU x 8 waves = 32 waves/CU = 8 waves/SIMD is
// (512,4): 64-VGPR budget, which R6 (more state) already met exactly. R6's 34%
// occupancy was GRID-limited (512 blocks = 2/CU); this grid supplies 4/CU.
__global__ __launch_bounds__(512, 4) void gemm_adc(const u16* __restrict__ qa,
                                                   const u16* __restrict__ wq,
                                                   const float* __restrict__ pmax,
                                                   float* __restrict__ out) {
  __shared__ __align__(16) u16 lB[6144];      // 12288 B: 3 runs x 64 rows x 32
  __shared__ __align__(16) u16 sA[6528];      // 13056 B: 204 px x 32 ch (rotated)
  __shared__ float sred[16];
  const int tid = threadIdx.x;
  float mx, mw;
  reduce_pmax(pmax, tid, 512, sred, mx, mw);

  const int mblk = blockIdx.x, nblk = blockIdx.y;
  const int b = mblk >> 3;
  const int p0 = (mblk & 7) * 128;        // pixel base (4 image rows of 32)
  const int y0 = (mblk & 7) * 4;          // slab top row in padded coords
  const int n0 = nblk * 64;
  const int lane = tid & 63, wv = tid >> 6;
  const int wm = (wv & 3) * 32, wn = (wv >> 2) * 32;
  const int fm = lane & 15, fq = lane >> 4;
  const int swz = (fq + ((fm >> 1) & 3)) & 3;

  double sa = (double)mx + 1e-12;
  double sw = (double)mw + 1e-12;
  double Sstep = sa * sw * 0.999 / 459.0;   // I/step = intsum * Sstep

  // ---- precompute 9 A-fragment LDS addresses (mi=0); mi offset is +512 ----
  const int OFS[9] = {0, 1, 2, 34, 35, 36, 68, 69, 70};   // rc*34 + ri
  int addrA9[9];
  {
    int pr = wm + fm;
    int pixb = (pr >> 5) * 34 + (pr & 31);
#pragma unroll
    for (int t = 0; t < 9; t++) {
      int P = pixb + OFS[t];
      addrA9[t] = P * 32 + (((fq + ((P >> 1) & 3)) & 3) << 3);
    }
  }
  // B read offsets (lane-constant); row stride 32 u16 (same proven pattern)
  int bno[2];
#pragma unroll
  for (int ni = 0; ni < 2; ni++) bno[ni] = (wn + ni * 16 + fm) * RUN + swz * 8;

  // B staging geometry: 768 slots; i0: s=tid (runs 0-1), i1: s=512+tid, tid<256
  // (run 2). row=(tid>>2)&63, jsrc identical for both loads (512 == 0 mod 8 slots).
  const int jsrc = ((tid & 3) - ((tid >> 3) & 3)) & 3;
  const u16* Bb = wq + (size_t)(n0 + ((tid >> 2) & 63)) * KTOT + jsrc * 8;
  const int brun0 = (tid >> 8) * RUN;     // k-offset of i0's run (0 or 32)

  // slab staging geometry: 816 slots; i0: s=tid (all), i1: s=512+tid (tid<304)
  const u16* Abase = qa + (size_t)b * QA_BSTRIDE + (size_t)y0 * PADH * NC;
  int soff[2], sdst[2];
#pragma unroll
  for (int i = 0; i < 2; i++) {
    int s = i * 512 + tid;
    soff[i] = (s >> 2) * NC + ((((s & 3) - ((s >> 3) & 3)) & 3) << 3);
    sdst[i] = s * 8;
  }

  floatx4 acc[2][2];
  float tot[2][2][4];
#pragma unroll
  for (int mi = 0; mi < 2; mi++)
#pragma unroll
    for (int ni = 0; ni < 2; ni++)
#pragma unroll
      for (int rr = 0; rr < 4; rr++) { acc[mi][ni][rr] = 0.f; tot[mi][ni][rr] = 0.f; }

  auto STAGE_SLAB = [&](int gp) {
    int cw = ((256 * gp) / 9) & ~3;
    const u16* srcg = Abase + cw;
    __builtin_amdgcn_global_load_lds((const AS1 void*)(srcg + soff[0]),
                                     (AS3 void*)&sA[sdst[0]], 16, 0, 0);
    if (tid < 304)
      __builtin_amdgcn_global_load_lds((const AS1 void*)(srcg + soff[1]),
                                       (AS3 void*)&sA[sdst[1]], 16, 0, 0);
  };
  auto STAGE_B = [&](int kb0) {
    __builtin_amdgcn_global_load_lds((const AS1 void*)(Bb + kb0 + brun0),
                                     (AS3 void*)&lB[tid * 8], 16, 0, 0);
    if (tid < 256)
      __builtin_amdgcn_global_load_lds((const AS1 void*)(Bb + kb0 + 2 * RUN),
                                       (AS3 void*)&lB[(512 + tid) * 8], 16, 0, 0);
  };
  auto FOLD = [&]() {
#pragma unroll
    for (int mi = 0; mi < 2; mi++)
#pragma unroll
      for (int ni = 0; ni < 2; ni++)
#pragma unroll
        for (int rr = 0; rr < 4; rr++) {
          double d = (double)acc[mi][ni][rr] * Sstep;
          float tf = (float)rint(d);
          tf = fminf(fmaxf(tf, -128.f), 127.f);
          tot[mi][ni][rr] += tf;
          acc[mi][ni][rr] = 0.f;
        }
  };

#pragma unroll 1
  for (int g = 0; g < NG; g++) {
    // stage slab(g) + B(g,rc=0); previous group's reads closed by its last barrier
    STAGE_SLAB(g);
    STAGE_B(g * GK);
    if (g > 0) FOLD();           // register-only, overlaps the in-flight loads
#pragma unroll
    for (int rc = 0; rc < 3; rc++) {
      __syncthreads();           // staged chunk landed (implicit vmcnt drain)
      // ---- 3 runs x 4 MFMA per wave ----
#pragma unroll
      for (int ri = 0; ri < 3; ri++) {
        short8 afr[2], bfr[2];
#pragma unroll
        for (int mi = 0; mi < 2; mi++)
          afr[mi] = *(const short8*)&sA[addrA9[rc * 3 + ri] + mi * 512];
#pragma unroll
        for (int ni = 0; ni < 2; ni++)
          bfr[ni] = *(const short8*)&lB[ri * 2048 + bno[ni]];
#pragma unroll
        for (int mi = 0; mi < 2; mi++)
#pragma unroll
          for (int ni = 0; ni < 2; ni++)
            acc[mi][ni] = __builtin_amdgcn_mfma_f32_16x16x32_bf16(afr[mi], bfr[ni], acc[mi][ni], 0, 0, 0);
      }
      __syncthreads();           // reads done before overwrite
      if (rc < 2) STAGE_B(g * GK + (rc + 1) * 96);
    }
  }
  // ---- final group's ADC fold ----
#pragma unroll
  for (int mi = 0; mi < 2; mi++)
#pragma unroll
    for (int ni = 0; ni < 2; ni++)
#pragma unroll
      for (int rr = 0; rr < 4; rr++) {
        double d = (double)acc[mi][ni][rr] * Sstep;
        float tf = (float)rint(d);
        tf = fminf(fmaxf(tf, -128.f), 127.f);
        tot[mi][ni][rr] += tf;
      }

  // ---- epilogue ----
#pragma unroll
  for (int mi = 0; mi < 2; mi++)
#pragma unroll
    for (int ni = 0; ni < 2; ni++) {
      int o = n0 + wn + ni * 16 + fm;
      int p = p0 + wm + mi * 16 + fq * 4;
      float4 o4;
      o4.x = tot[mi][ni][0] * 1e-3f;
      o4.y = tot[mi][ni][1] * 1e-3f;
      o4.z = tot[mi][ni][2] * 1e-3f;
      o4.w = tot[mi][ni][3] * 1e-3f;
      *(float4*)(out + ((size_t)(b * NO + o)) * NPIX + p) = o4;
    }
}

extern "C" void kernel_launch(void* const* d_in, const int* in_sizes, int n_in,
                              void* d_out, int out_size, void* d_ws, size_t ws_size,
                              hipStream_t stream) {
  const float* x = (const float*)d_in[0];
  const float* w = (const float*)d_in[1];
  float* out = (float*)d_out;

  float* pmax = (float*)d_ws;                                // 1088 slots
  u16* qa = (u16*)((char*)d_ws + 8192);                      // padded acts: 18,939,904 B
  u16* wq = (u16*)((char*)d_ws + 8192 + 18939904 + 8192);    // weights: 256*2592*2 B

  fused_pre<<<1376, 256, 0, stream>>>((const float4*)x, (NB * NC * NH * NW) / 4,
                                      (const float4*)w, (NO * NC * KPIX) / 4,
                                      pmax, qa);
  fused_quant<<<1024 + 2592, 256, 0, stream>>>(x, w, pmax, qa, wq, out + (out_size - 1));
  gemm_adc<<<dim3(256, 4), 512, 0, stream>>>(qa, wq, pmax, out);
}